// Round 3
// baseline (2344.457 us; speedup 1.0000x reference)
//
#include <hip/hip_runtime.h>

#define HID 256
#define T_STEPS 1024
#define F_IN 40
#define NSPK 1251
#define NCHUNK 8
#define K2_THREADS 512

// grid: 192 blocks, active iff bid%8==0 -> 24 active blocks, all (hopefully) on XCD0
#define K2_GRID 192

// workspace layout (bytes):
//   hloc  : u64 [3][1025][256]  (local-L2 exchange, plain stores)
#define HLOC_BYTES ((size_t)3 * 1025 * 256 * 8)
//   hglob : u64 [3][1025][256]  (agent-scope mirror, fallback + cross-layer)
#define HGLOB_OFF  HLOC_BYTES
#define HGLOB_BYTES HLOC_BYTES
//   xg    : f32 [1024][1024]    (layer-0 input projection, precomputed)
#define XG_OFF     (HGLOB_OFF + HGLOB_BYTES)
#define XG_BYTES   ((size_t)1024 * 1024 * 4)
//   h2f   : f32 [1024][256]     (layer-2 h, plain floats for the GEMM)
#define H2F_OFF    (XG_OFF + XG_BYTES)

__device__ __forceinline__ float fast_sig(float v) {
    return __builtin_amdgcn_rcpf(1.f + __expf(-v));
}
__device__ __forceinline__ float fast_tanh(float v) {
    return 2.f * __builtin_amdgcn_rcpf(1.f + __expf(-2.f * v)) - 1.f;
}

// L1-bypassing, L2-served 8B load (sc0). Correct for same-XCD producer/consumer.
__device__ __forceinline__ unsigned long long ld_l2(const unsigned long long* p) {
    unsigned long long v;
    asm volatile("global_load_dwordx2 %0, %1, off sc0\n\ts_waitcnt vmcnt(0)"
                 : "=v"(v) : "v"(p) : "memory");
    return v;
}

// Hybrid spin: fast sc0 polls on the local buffer, every 4th poll an agent-scope
// load on the mirror (guarantees progress if blocks land on different XCDs).
__device__ __forceinline__ float wait_tagged(const unsigned long long* pl,
                                             const unsigned long long* pg,
                                             unsigned want) {
    unsigned long long v = ld_l2(pl);
    int n = 0;
    while ((unsigned)(v >> 32) != want) {
        v = ((++n & 3) == 0)
              ? __hip_atomic_load(pg, __ATOMIC_RELAXED, __HIP_MEMORY_SCOPE_AGENT)
              : ld_l2(pl);
    }
    return __uint_as_float((unsigned)v);
}

// Dual publish: plain store -> local L2 (fast same-XCD path), agent store -> L3.
__device__ __forceinline__ void publish(unsigned long long* pl, unsigned long long* pg,
                                        unsigned tag, float val) {
    unsigned long long w = ((unsigned long long)tag << 32) | (unsigned long long)__float_as_uint(val);
    *(volatile unsigned long long*)pl = w;
    __hip_atomic_store(pg, w, __ATOMIC_RELAXED, __HIP_MEMORY_SCOPE_AGENT);
}

// ---------------- K0: init tags for t=0 ----------------
__global__ void k0_init(unsigned long long* __restrict__ hloc,
                        unsigned long long* __restrict__ hglob) {
    int tid = threadIdx.x;
    if (tid < 3 * HID) {
        int l = tid / HID, k = tid % HID;
        size_t idx = (size_t)(l * 1025 + 0) * HID + k;
        hloc[idx] = 0ull;    // tag 0, value 0.0f
        hglob[idx] = 0ull;
    }
}

// ---------------- K1: xg[t][r] = sum_k w_ih0[r][k] * x[63][t][k] ----------------
__global__ __launch_bounds__(256) void k1_xproj(const float* __restrict__ x,
                                                const float* __restrict__ w_ih0,
                                                float* __restrict__ xg) {
    __shared__ float xs[8][F_IN];
    int b = blockIdx.x, tid = threadIdx.x;
    const float* x63 = x + (size_t)63 * T_STEPS * F_IN + (size_t)b * 8 * F_IN;
    for (int i = tid; i < 8 * F_IN; i += 256) xs[i / F_IN][i % F_IN] = x63[i];
    __syncthreads();
    for (int rr = 0; rr < 4; rr++) {
        int r = tid + rr * 256;
        float wrow[F_IN];
        #pragma unroll
        for (int k = 0; k < F_IN; k++) wrow[k] = w_ih0[r * F_IN + k];
        #pragma unroll
        for (int tt = 0; tt < 8; tt++) {
            float a = 0.f;
            #pragma unroll
            for (int k = 0; k < F_IN; k++) a += wrow[k] * xs[tt][k];
            xg[(size_t)(b * 8 + tt) * 1024 + r] = a;
        }
    }
}

// ---------------- K2: pipelined 3-layer LSTM ----------------
__global__ __launch_bounds__(K2_THREADS, 2) void k2_lstm(
    const float* __restrict__ w_ih1, const float* __restrict__ w_hh0,
    const float* __restrict__ b_ih0, const float* __restrict__ b_hh0,
    const float* __restrict__ w_hh1,
    const float* __restrict__ b_ih1, const float* __restrict__ b_hh1,
    const float* __restrict__ w_ih2, const float* __restrict__ w_hh2,
    const float* __restrict__ b_ih2, const float* __restrict__ b_hh2,
    const float* __restrict__ xg,
    unsigned long long* __restrict__ hloc, unsigned long long* __restrict__ hglob,
    float* __restrict__ h2f)
{
    const int bid = blockIdx.x;
    if ((bid & 7) != 0) return;          // keep only XCD-0 blocks (assuming bid%8 round-robin)
    const int idx = bid >> 3;            // 0..23
    if (idx >= 24) return;
    const int layer = idx >> 3;          // 0..2
    const int g     = idx & 7;           // chunk of 32 h-indices
    const int tid   = threadIdx.x;
    const int row_idx = tid >> 2;        // 0..127
    const int seg     = tid & 3;         // k-segment
    const int q  = row_idx >> 5;         // gate 0..3 (i,f,g,o)
    const int jj = row_idx & 31;
    const int r  = q * 256 + g * 32 + jj;

    const float* wih = (layer == 1) ? w_ih1 : w_ih2;   // layer0: unused (xg precomputed)
    const float* whh = (layer == 0) ? w_hh0 : (layer == 1) ? w_hh1 : w_hh2;
    const float* bih = (layer == 0) ? b_ih0 : (layer == 1) ? b_ih1 : b_ih2;
    const float* bhh = (layer == 0) ? b_hh0 : (layer == 1) ? b_hh1 : b_hh2;

    // LDS: [0..511] prev-layer h double buffer, [512..767] own h, [768..895] gates
    __shared__ float lds_all[896];

    // ---- register-resident weights, pre-rotated by seg*8 floats ----
    float w[128];
    const int rot4 = 2 * seg;
    if (seg >= 2) {
        const float4* src = (const float4*)(whh + (size_t)r * HID + (seg - 2) * 128);
        #pragma unroll
        for (int k4 = 0; k4 < 32; k4++) {
            float4 v = src[(k4 + rot4) & 31];
            w[k4 * 4 + 0] = v.x; w[k4 * 4 + 1] = v.y;
            w[k4 * 4 + 2] = v.z; w[k4 * 4 + 3] = v.w;
        }
    } else if (layer > 0) {
        const float4* src = (const float4*)(wih + (size_t)r * HID + seg * 128);
        #pragma unroll
        for (int k4 = 0; k4 < 32; k4++) {
            float4 v = src[(k4 + rot4) & 31];
            w[k4 * 4 + 0] = v.x; w[k4 * 4 + 1] = v.y;
            w[k4 * 4 + 2] = v.z; w[k4 * 4 + 3] = v.w;
        }
    } else {
        #pragma unroll
        for (int k = 0; k < 128; k++) w[k] = 0.f;
    }
    float bias = (seg == 0) ? (bih[r] + bhh[r]) : 0.f;

    for (int i = tid; i < 896; i += K2_THREADS) lds_all[i] = 0.f;
    __syncthreads();

    unsigned long long* h_own_loc  = hloc  + (size_t)layer * 1025 * HID;
    unsigned long long* h_own_glob = hglob + (size_t)layer * 1025 * HID;
    const unsigned long long* h_prev_loc  = hloc  + (size_t)(layer - 1) * 1025 * HID;
    const unsigned long long* h_prev_glob = hglob + (size_t)(layer - 1) * 1025 * HID;

    // pre-fill prev buffer 0 with prev-layer h[1] (layers 1,2)
    if (layer > 0 && tid >= 256) {
        int j = tid - 256;
        lds_all[j] = wait_tagged(h_prev_loc + (size_t)1 * HID + j,
                                 h_prev_glob + (size_t)1 * HID + j, 1u);
    }
    __syncthreads();

    float c_state = 0.f;
    const int rot = seg * 8;

    for (int t = 0; t < T_STEPS; t++) {
        float xgv = 0.f;
        if (layer == 0 && seg == 0) xgv = xg[(size_t)t * 1024 + r];  // early issue, used post-dot

        if (tid < 256) {
            // own-layer h[t], tag t
            lds_all[512 + tid] = wait_tagged(h_own_loc + (size_t)t * HID + tid,
                                             h_own_glob + (size_t)t * HID + tid, (unsigned)t);
        } else if (layer > 0 && t + 2 <= T_STEPS) {
            // prefetch prev-layer h[t+2] for NEXT step into the other buffer
            int j = tid - 256;
            lds_all[((t + 1) & 1) * 256 + j] =
                wait_tagged(h_prev_loc + (size_t)(t + 2) * HID + j,
                            h_prev_glob + (size_t)(t + 2) * HID + j, (unsigned)(t + 2));
        }
        __syncthreads();

        // ---- dot: segs 0,1 -> prev-layer buffer (this step's), segs 2,3 -> own h ----
        const float* in = (seg < 2) ? (lds_all + (t & 1) * 256 + seg * 128)
                                    : (lds_all + 512 + (seg - 2) * 128);
        float acc = 0.f;
        #pragma unroll
        for (int k4 = 0; k4 < 32; k4++) {
            int base = (k4 * 4 + rot) & 127;
            acc += w[k4 * 4 + 0] * in[base + 0];
            acc += w[k4 * 4 + 1] * in[base + 1];
            acc += w[k4 * 4 + 2] * in[base + 2];
            acc += w[k4 * 4 + 3] * in[base + 3];
        }
        acc += __shfl_xor(acc, 1, 64);
        acc += __shfl_xor(acc, 2, 64);
        if (seg == 0) lds_all[768 + row_idx] = acc + bias + xgv;
        __syncthreads();

        if (tid < 32) {
            float gi = lds_all[768 + tid];
            float gf = lds_all[768 + 32 + tid];
            float gg = lds_all[768 + 64 + tid];
            float go = lds_all[768 + 96 + tid];
            float si = fast_sig(gi);
            float sf = fast_sig(gf);
            float so = fast_sig(go);
            c_state = sf * c_state + si * fast_tanh(gg);
            float hv = so * fast_tanh(c_state);
            size_t oidx = (size_t)(t + 1) * HID + g * 32 + tid;
            publish(h_own_loc + oidx, h_own_glob + oidx, (unsigned)(t + 1), hv);
            if (layer == 2) h2f[(size_t)t * HID + g * 32 + tid] = hv;
        }
    }
}

// ---------------- K3: logits = h2 @ w_lin^T + b_lin ----------------
#define BM 64
#define BN 64
#define BK 32
__global__ __launch_bounds__(256) void k3_logits(
    const float* __restrict__ A, const float* __restrict__ w_lin,
    const float* __restrict__ b_lin, float* __restrict__ out)
{
    int m0 = blockIdx.x * BM;
    int n0 = blockIdx.y * BN;
    int tid = threadIdx.x;
    __shared__ float As[BM][BK + 1];
    __shared__ float Bs[BN][BK + 1];
    float accv[4][4] = {};
    int tx = tid % 16, ty = tid / 16;

    for (int k0 = 0; k0 < HID; k0 += BK) {
        int row = tid / 4;
        int kq  = (tid % 4) * 8;
        {
            const float4* src = (const float4*)(A + (size_t)(m0 + row) * HID + k0 + kq);
            float4 v0 = src[0], v1 = src[1];
            As[row][kq + 0] = v0.x; As[row][kq + 1] = v0.y; As[row][kq + 2] = v0.z; As[row][kq + 3] = v0.w;
            As[row][kq + 4] = v1.x; As[row][kq + 5] = v1.y; As[row][kq + 6] = v1.z; As[row][kq + 7] = v1.w;
        }
        {
            int n = n0 + row;
            float4 v0 = make_float4(0.f, 0.f, 0.f, 0.f), v1 = v0;
            if (n < NSPK) {
                const float4* src = (const float4*)(w_lin + (size_t)n * HID + k0 + kq);
                v0 = src[0]; v1 = src[1];
            }
            Bs[row][kq + 0] = v0.x; Bs[row][kq + 1] = v0.y; Bs[row][kq + 2] = v0.z; Bs[row][kq + 3] = v0.w;
            Bs[row][kq + 4] = v1.x; Bs[row][kq + 5] = v1.y; Bs[row][kq + 6] = v1.z; Bs[row][kq + 7] = v1.w;
        }
        __syncthreads();
        #pragma unroll
        for (int kk = 0; kk < BK; kk++) {
            float a0 = As[ty * 4 + 0][kk], a1 = As[ty * 4 + 1][kk];
            float a2 = As[ty * 4 + 2][kk], a3 = As[ty * 4 + 3][kk];
            float b0 = Bs[tx * 4 + 0][kk], b1 = Bs[tx * 4 + 1][kk];
            float b2 = Bs[tx * 4 + 2][kk], b3 = Bs[tx * 4 + 3][kk];
            accv[0][0] += a0 * b0; accv[0][1] += a0 * b1; accv[0][2] += a0 * b2; accv[0][3] += a0 * b3;
            accv[1][0] += a1 * b0; accv[1][1] += a1 * b1; accv[1][2] += a1 * b2; accv[1][3] += a1 * b3;
            accv[2][0] += a2 * b0; accv[2][1] += a2 * b1; accv[2][2] += a2 * b2; accv[2][3] += a2 * b3;
            accv[3][0] += a3 * b0; accv[3][1] += a3 * b1; accv[3][2] += a3 * b2; accv[3][3] += a3 * b3;
        }
        __syncthreads();
    }
    #pragma unroll
    for (int i = 0; i < 4; i++) {
        int m = m0 + ty * 4 + i;
        #pragma unroll
        for (int j = 0; j < 4; j++) {
            int n = n0 + tx * 4 + j;
            if (n < NSPK) out[(size_t)m * NSPK + n] = accv[i][j] + b_lin[n];
        }
    }
}

// ---------------- K4: in-place row-wise log_softmax ----------------
__global__ __launch_bounds__(256) void k4_logsoftmax(float* __restrict__ out)
{
    int t = blockIdx.x;
    float* row = out + (size_t)t * NSPK;
    int tid = threadIdx.x;
    __shared__ float red[8];
    float vals[5];
    float lmax = -1e30f;
    #pragma unroll
    for (int k = 0; k < 5; k++) {
        int n = tid + k * 256;
        vals[k] = (n < NSPK) ? row[n] : -1e30f;
        lmax = fmaxf(lmax, vals[k]);
    }
    #pragma unroll
    for (int m = 1; m < 64; m <<= 1) lmax = fmaxf(lmax, __shfl_xor(lmax, m, 64));
    int wave = tid >> 6;
    if ((tid & 63) == 0) red[wave] = lmax;
    __syncthreads();
    float gmax = fmaxf(fmaxf(red[0], red[1]), fmaxf(red[2], red[3]));
    float lsum = 0.f;
    #pragma unroll
    for (int k = 0; k < 5; k++) {
        int n = tid + k * 256;
        if (n < NSPK) lsum += __expf(vals[k] - gmax);
    }
    #pragma unroll
    for (int m = 1; m < 64; m <<= 1) lsum += __shfl_xor(lsum, m, 64);
    if ((tid & 63) == 0) red[4 + wave] = lsum;
    __syncthreads();
    float lse = logf(red[4] + red[5] + red[6] + red[7]) + gmax;
    #pragma unroll
    for (int k = 0; k < 5; k++) {
        int n = tid + k * 256;
        if (n < NSPK) row[n] = vals[k] - lse;
    }
}

extern "C" void kernel_launch(void* const* d_in, const int* in_sizes, int n_in,
                              void* d_out, int out_size, void* d_ws, size_t ws_size,
                              hipStream_t stream) {
    const float* x     = (const float*)d_in[0];
    const float* w_ih0 = (const float*)d_in[1];
    const float* w_hh0 = (const float*)d_in[2];
    const float* b_ih0 = (const float*)d_in[3];
    const float* b_hh0 = (const float*)d_in[4];
    const float* w_ih1 = (const float*)d_in[5];
    const float* w_hh1 = (const float*)d_in[6];
    const float* b_ih1 = (const float*)d_in[7];
    const float* b_hh1 = (const float*)d_in[8];
    const float* w_ih2 = (const float*)d_in[9];
    const float* w_hh2 = (const float*)d_in[10];
    const float* b_ih2 = (const float*)d_in[11];
    const float* b_hh2 = (const float*)d_in[12];
    const float* w_lin = (const float*)d_in[13];
    const float* b_lin = (const float*)d_in[14];

    unsigned long long* hloc  = (unsigned long long*)d_ws;
    unsigned long long* hglob = (unsigned long long*)((char*)d_ws + HGLOB_OFF);
    float* xg  = (float*)((char*)d_ws + XG_OFF);
    float* h2f = (float*)((char*)d_ws + H2F_OFF);
    float* out = (float*)d_out;

    k0_init<<<1, 1024, 0, stream>>>(hloc, hglob);
    k1_xproj<<<128, 256, 0, stream>>>(x, w_ih0, xg);
    k2_lstm<<<K2_GRID, K2_THREADS, 0, stream>>>(
        w_ih1, w_hh0, b_ih0, b_hh0,
        w_hh1, b_ih1, b_hh1,
        w_ih2, w_hh2, b_ih2, b_hh2,
        xg, hloc, hglob, h2f);
    k3_logits<<<dim3(16, 20), 256, 0, stream>>>(h2f, w_lin, b_lin, out);
    k4_logsoftmax<<<T_STEPS, 256, 0, stream>>>(out);
}